// Round 16
// baseline (697.120 us; speedup 1.0000x reference)
//
#include <hip/hip_runtime.h>
#include <cstddef>

// Problem constants (from reference setup_inputs)
static constexpr int NN   = 100000;   // nodes
static constexpr int NE   = 3200000;  // edges
static constexpr int CIN  = 512;
static constexpr int CHID = 40;
static constexpr int COUT = 20;

// LDS-histogram CSR build geometry
static constexpr int NCH    = 32;            // edge chunks
static constexpr int CHUNK_E = NE / NCH;     // 100000 edges per chunk (div by 4)
static constexpr int NRANGE = 8;             // node ranges
static constexpr int RANGE  = NN / NRANGE;   // 12500 nodes -> 50 KB LDS histogram

// clang native vector type (HIP float4 rejected by NT builtins -- R9 lesson)
typedef float f32x4 __attribute__((ext_vector_type(4)));

#define GLB_AS __attribute__((address_space(1)))
#define LDS_AS __attribute__((address_space(3)))

// ---------------- CSR build (LDS histograms; NO memory-side atomics) ----------------
// R12 lesson: global-memory atomics execute at the TCC regardless of scope.
// R13 measured: LDS-histogram build removed the 149-167us atomic kernel. FROZEN.

__global__ __launch_bounds__(1024) void k_histA(const int* __restrict__ dst,
                                                int* __restrict__ cntb) {
  __shared__ int hc[RANGE];  // 50 KB
  const int c  = blockIdx.x >> 3;    // chunk 0..31
  const int r0 = (blockIdx.x & 7) * RANGE;
  for (int i = threadIdx.x; i < RANGE; i += 1024) hc[i] = 0;
  __syncthreads();
  const int base = c * (CHUNK_E / 4);
  const int end  = base + CHUNK_E / 4;
  for (int i = base + (int)threadIdx.x; i < end; i += 1024) {
    const int4 d = ((const int4*)dst)[i];
    if ((unsigned)(d.x - r0) < (unsigned)RANGE) atomicAdd(&hc[d.x - r0], 1);
    if ((unsigned)(d.y - r0) < (unsigned)RANGE) atomicAdd(&hc[d.y - r0], 1);
    if ((unsigned)(d.z - r0) < (unsigned)RANGE) atomicAdd(&hc[d.z - r0], 1);
    if ((unsigned)(d.w - r0) < (unsigned)RANGE) atomicAdd(&hc[d.w - r0], 1);
  }
  __syncthreads();
  int* __restrict__ outp = cntb + (size_t)c * NN + r0;
  for (int i = threadIdx.x; i < RANGE; i += 1024) outp[i] = hc[i];
}

// per node: exclusive prefix across the 32 chunk-copies (in place) + total.
__global__ __launch_bounds__(256) void k_merge(int* __restrict__ cntb, int* __restrict__ cnt, int n) {
  const int i = blockIdx.x * 256 + threadIdx.x;
  if (i >= n) return;
  int s = 0;
#pragma unroll 8
  for (int b = 0; b < NCH; ++b) {
    int* p = cntb + (size_t)b * NN + i;
    const int t = *p;
    *p = s;
    s += t;
  }
  cnt[i] = s;
}

// block of 256 scans 1024 elements; fused dinv = rsqrt(cnt+1).
__global__ __launch_bounds__(256) void k_scanA(const int* __restrict__ cnt, int* __restrict__ excl,
                                               int* __restrict__ bsums, float* __restrict__ dinv, int n) {
  __shared__ int sdata[256];
  const int t = threadIdx.x;
  const int base = blockIdx.x * 1024 + t * 4;
  int v[4];
#pragma unroll
  for (int j = 0; j < 4; ++j) {
    const int i = base + j;
    v[j] = (i < n) ? cnt[i] : 0;
    if (i < n) dinv[i] = rsqrtf((float)(v[j] + 1));
  }
  const int s4 = v[0] + v[1] + v[2] + v[3];
  sdata[t] = s4;
  __syncthreads();
  for (int off = 1; off < 256; off <<= 1) {
    int val = 0;
    if (t >= off) val = sdata[t - off];
    __syncthreads();
    sdata[t] += val;
    __syncthreads();
  }
  int run = sdata[t] - s4;  // exclusive prefix of this thread's 4 items
#pragma unroll
  for (int j = 0; j < 4; ++j) {
    const int i = base + j;
    if (i < n) excl[i] = run;
    run += v[j];
  }
  if (t == 255) bsums[blockIdx.x] = sdata[255];
}

__global__ __launch_bounds__(256) void k_scanB(int* __restrict__ bsums, int nb) {
  __shared__ int sdata[256];
  const int t = threadIdx.x;
  const int v = (t < nb) ? bsums[t] : 0;
  sdata[t] = v;
  __syncthreads();
  for (int off = 1; off < 256; off <<= 1) {
    int val = 0;
    if (t >= off) val = sdata[t - off];
    __syncthreads();
    sdata[t] += val;
    __syncthreads();
  }
  if (t < nb) bsums[t] = sdata[t] - v;  // exclusive, in place
}

__global__ __launch_bounds__(256) void k_scanC(int* __restrict__ rowptr, const int* __restrict__ boff,
                                               int n, int n_edges) {
  const int i = blockIdx.x * 256 + threadIdx.x;
  if (i < n) rowptr[i] += boff[i >> 10];
  if (i == 0) rowptr[n] = n_edges;
}

// Pass B: re-read chunk, re-run LDS histogram for local ranks, place edges.
__global__ __launch_bounds__(1024) void k_histFill(const int* __restrict__ src,
                                                   const int* __restrict__ dst,
                                                   const int* __restrict__ rowptr,
                                                   const int* __restrict__ cntb,
                                                   int* __restrict__ csr_src) {
  __shared__ int hc[RANGE];  // 50 KB
  const int c  = blockIdx.x >> 3;
  const int r0 = (blockIdx.x & 7) * RANGE;
  for (int i = threadIdx.x; i < RANGE; i += 1024) hc[i] = 0;
  __syncthreads();
  const int* __restrict__ cbo = cntb + (size_t)c * NN;
  const int base = c * (CHUNK_E / 4);
  const int end  = base + CHUNK_E / 4;
  for (int i = base + (int)threadIdx.x; i < end; i += 1024) {
    const int4 d = ((const int4*)dst)[i];
    const int4 s = ((const int4*)src)[i];
    if ((unsigned)(d.x - r0) < (unsigned)RANGE) {
      const int rk = atomicAdd(&hc[d.x - r0], 1);
      csr_src[rowptr[d.x] + cbo[d.x] + rk] = s.x;
    }
    if ((unsigned)(d.y - r0) < (unsigned)RANGE) {
      const int rk = atomicAdd(&hc[d.y - r0], 1);
      csr_src[rowptr[d.y] + cbo[d.y] + rk] = s.y;
    }
    if ((unsigned)(d.z - r0) < (unsigned)RANGE) {
      const int rk = atomicAdd(&hc[d.z - r0], 1);
      csr_src[rowptr[d.z] + cbo[d.z] + rk] = s.z;
    }
    if ((unsigned)(d.w - r0) < (unsigned)RANGE) {
      const int rk = atomicAdd(&hc[d.w - r0], 1);
      csr_src[rowptr[d.w] + cbo[d.w] + rk] = s.w;
    }
  }
}

// ---------------- GEMM 1: W in LDS (kills SMEM lgkmcnt(0) serialization) ----------------
// R13/R14/R15: FOUR staging variants all pin at ~149us with identical counters
// -- the conserved element is the COMPUTE LOOP. Theory: W reads are wave-
// uniform -> compiler emits s_load; SMEM returns OUT-OF-ORDER on CDNA, so
// every use needs a full lgkmcnt(0) drain (which also drains the in-order
// ds_read queue); and one k4 of W = 40 SGPRs vs ~100 budget, so s_loads
// can't batch deeper than ~1 iteration. Result: ~460cyc serialized per k4
// = 149us regardless of staging. Fix: stage the W tile in LDS (contiguous
// 10KB coalesced copy; W is L2-hot) and read it with wave-uniform ds_read
// float2 (LDS broadcast: in-order, precise lgkmcnt(N), ~free bandwidth).
// 8 K-tiles of 64: x tile 16KB (global_load_lds + pre-swizzled source,
// aux=2 NT -- R11 victim-write fix) + W tile 10KB = 26.6KB -> 6 blocks/CU.
// Per-acc[j] k-order unchanged -> bit-identical output (absmax 4.88e-4).
__global__ __launch_bounds__(256) void k_gemm1(const float* __restrict__ x, const float* __restrict__ W,
                                               float* __restrict__ h, int n) {
  __shared__ float xw[64 * 64];   // 16 KB x tile; reused as output staging [64][44]
  __shared__ float wt[64 * CHID]; // 10 KB W tile (dense [64][40], 8B-aligned rows)
  const int t    = threadIdx.x;
  const int nd   = t & 63;                                   // node-in-tile (compute)
  const int g    = __builtin_amdgcn_readfirstlane(t >> 6);   // wave 0..3 (wave-uniform)
  const int lane = t & 63;
  const int block0 = blockIdx.x * 64;

  float acc[10];
#pragma unroll
  for (int j = 0; j < 10; ++j) acc[j] = 0.f;

  for (int kt = 0; kt < 8; ++kt) {
    if (kt) __syncthreads();  // previous tile fully consumed

    // ---- x tile: 4 global_load_lds calls per wave (wave g owns rows g*16..g*16+15)
    // lane l covers row rowbase+(l>>4), slot l&15; slot s holds global col4
    // s^(row&15) (pre-swizzled source), LDS dest linear = base + l*16.
#pragma unroll
    for (int j = 0; j < 4; ++j) {
      const int rowbase = g * 16 + j * 4;
      const int row = rowbase + (lane >> 4);
      int gn = block0 + row;
      if (gn >= n) gn = n - 1;  // clamp: valid memory, h-store is guarded
      const int col4 = (lane & 15) ^ (row & 15);
      const float* gp = x + (size_t)gn * CIN + kt * 64 + col4 * 4;
      float* lp = &xw[rowbase * 64];  // wave-uniform LDS base
      __builtin_amdgcn_global_load_lds((const GLB_AS void*)gp, (LDS_AS void*)lp,
                                       16, 0, 2 /*CPol NT*/);
    }

    // ---- W tile: contiguous [64][40] block = 2560 floats; coalesced f32x4 copy.
    {
      const float* __restrict__ Wb = W + (size_t)kt * 64 * CHID;
#pragma unroll
      for (int r = 0; r < 3; ++r) {
        const int lin = t + 256 * r;
        if (lin < 640) {
          *(f32x4*)&wt[lin * 4] = *(const f32x4*)(Wb + (size_t)lin * 4);
        }
      }
    }
    __syncthreads();  // tile ready (vmcnt+lgkmcnt drained by barrier)

    // ---- compute: 64 k-values, 10 channels per thread; W via LDS broadcast
#pragma unroll 4
    for (int k4 = 0; k4 < 16; ++k4) {
      const int byte = nd * 256 + ((k4 * 16) ^ ((nd & 15) << 4));
      const f32x4 xv = *(const f32x4*)((const char*)xw + byte);
      const float xk[4] = {xv.x, xv.y, xv.z, xv.w};
#pragma unroll
      for (int kk = 0; kk < 4; ++kk) {
        const float* __restrict__ wr = &wt[(k4 * 4 + kk) * CHID + g * 10];
        const float2 w0 = *(const float2*)(wr + 0);
        const float2 w1 = *(const float2*)(wr + 2);
        const float2 w2 = *(const float2*)(wr + 4);
        const float2 w3 = *(const float2*)(wr + 6);
        const float2 w4 = *(const float2*)(wr + 8);
        const float xs = xk[kk];
        acc[0] = fmaf(xs, w0.x, acc[0]);
        acc[1] = fmaf(xs, w0.y, acc[1]);
        acc[2] = fmaf(xs, w1.x, acc[2]);
        acc[3] = fmaf(xs, w1.y, acc[3]);
        acc[4] = fmaf(xs, w2.x, acc[4]);
        acc[5] = fmaf(xs, w2.y, acc[5]);
        acc[6] = fmaf(xs, w3.x, acc[6]);
        acc[7] = fmaf(xs, w3.y, acc[7]);
        acc[8] = fmaf(xs, w4.x, acc[8]);
        acc[9] = fmaf(xs, w4.y, acc[9]);
      }
    }
  }

  // ---- coalesced epilogue through LDS (xw reused; [64][44] = 11.3KB <= 16KB) ----
  __syncthreads();  // all waves done reading xw
#pragma unroll
  for (int j = 0; j < 10; ++j) xw[nd * 44 + g * 10 + j] = acc[j];
  __syncthreads();
  // 64 rows x 40 floats = 640 float4, contiguous across the block's h region
  for (int i = t; i < 640; i += 256) {
    const int row = i / 10;
    const int c   = i % 10;
    const int node = block0 + row;
    if (node < n)
      ((float4*)(h + (size_t)node * CHID))[c] = *(const float4*)&xw[row * 44 + c * 4];
  }
}

__global__ __launch_bounds__(256) void k_gemm2(const float* __restrict__ t1, const float* __restrict__ W,
                                               float* __restrict__ g, int n) {
  const int node = blockIdx.x * 256 + threadIdx.x;
  if (node >= n) return;
  const float4* __restrict__ r4 = (const float4*)(t1 + (size_t)node * CHID);
  float acc[COUT];
#pragma unroll
  for (int c = 0; c < COUT; ++c) acc[c] = 0.f;
#pragma unroll
  for (int kk = 0; kk < CHID / 4; ++kk) {
    const float4 xv = r4[kk];
    const float* __restrict__ Wk = W + kk * 4 * COUT;
#pragma unroll
    for (int c = 0; c < COUT; ++c) {
      float a = acc[c];
      a = fmaf(xv.x, Wk[c], a);
      a = fmaf(xv.y, Wk[COUT + c], a);
      a = fmaf(xv.z, Wk[2 * COUT + c], a);
      a = fmaf(xv.w, Wk[3 * COUT + c], a);
      acc[c] = a;
    }
  }
  float* __restrict__ o = g + (size_t)node * COUT;
#pragma unroll
  for (int c = 0; c < COUT; ++c) o[c] = acc[c];
}

// ---------------- CSR aggregation ----------------
// Layer 1 (CH=40): float2 channel-packing — 20 lanes/node, 3 nodes/wave.
__global__ __launch_bounds__(256) void k_agg40(const float* __restrict__ h, const int* __restrict__ rowptr,
                                               const int* __restrict__ csr_src, const float* __restrict__ dinv,
                                               const float* __restrict__ bias, float* __restrict__ out, int n) {
  const int wave = (blockIdx.x * 256 + (int)threadIdx.x) >> 6;
  const int lane = threadIdx.x & 63;
  const int sub  = lane / 20;   // 0..2 active; 3 => idle lanes 60..63
  const int cp   = lane % 20;   // channel pair: channels {2cp, 2cp+1}
  const int node = wave * 3 + sub;
  if (sub >= 3 || node >= n) return;
  const float2* __restrict__ h2 = (const float2*)h;
  const int r0 = rowptr[node];
  const int r1 = rowptr[node + 1];
  const float dv = dinv[node];
  const float self_w = dv * dv;  // self-loop norm = 1/deg
  float2 acc = h2[(size_t)node * 20 + cp];
  acc.x *= self_w;
  acc.y *= self_w;
  int i = r0;
  for (; i + 4 <= r1; i += 4) {
    const int s0 = csr_src[i + 0];
    const int s1 = csr_src[i + 1];
    const int s2 = csr_src[i + 2];
    const int s3 = csr_src[i + 3];
    const float w0 = dinv[s0] * dv;
    const float w1 = dinv[s1] * dv;
    const float w2 = dinv[s2] * dv;
    const float w3 = dinv[s3] * dv;
    const float2 g0 = h2[(size_t)s0 * 20 + cp];
    const float2 g1 = h2[(size_t)s1 * 20 + cp];
    const float2 g2 = h2[(size_t)s2 * 20 + cp];
    const float2 g3 = h2[(size_t)s3 * 20 + cp];
    acc.x = fmaf(g0.x, w0, acc.x); acc.y = fmaf(g0.y, w0, acc.y);
    acc.x = fmaf(g1.x, w1, acc.x); acc.y = fmaf(g1.y, w1, acc.y);
    acc.x = fmaf(g2.x, w2, acc.x); acc.y = fmaf(g2.y, w2, acc.y);
    acc.x = fmaf(g3.x, w3, acc.x); acc.y = fmaf(g3.y, w3, acc.y);
  }
  for (; i < r1; ++i) {
    const int s = csr_src[i];
    const float w = dinv[s] * dv;
    const float2 g = h2[(size_t)s * 20 + cp];
    acc.x = fmaf(g.x, w, acc.x);
    acc.y = fmaf(g.y, w, acc.y);
  }
  const float2 bv = ((const float2*)bias)[cp];
  float2 v;
  v.x = fmaxf(acc.x + bv.x, 0.f);  // ReLU (layer 1 only)
  v.y = fmaxf(acc.y + bv.y, 0.f);
  ((float2*)out)[(size_t)node * 20 + cp] = v;
}

// Layer 2 (CH=20): float2 packing — 10 lanes/node, 6 nodes/wave.
__global__ __launch_bounds__(256) void k_agg20(const float* __restrict__ h, const int* __restrict__ rowptr,
                                               const int* __restrict__ csr_src, const float* __restrict__ dinv,
                                               const float* __restrict__ bias, float* __restrict__ out, int n) {
  const int wave = (blockIdx.x * 256 + (int)threadIdx.x) >> 6;
  const int lane = threadIdx.x & 63;
  const int sub  = lane / 10;   // 0..5 active; 6 => idle lanes 60..63
  const int cp   = lane % 10;   // channel pair: channels {2cp, 2cp+1}
  const int node = wave * 6 + sub;
  if (sub >= 6 || node >= n) return;
  const float2* __restrict__ h2 = (const float2*)h;
  const int r0 = rowptr[node];
  const int r1 = rowptr[node + 1];
  const float dv = dinv[node];
  const float self_w = dv * dv;
  float2 acc = h2[(size_t)node * 10 + cp];
  acc.x *= self_w;
  acc.y *= self_w;
  int i = r0;
  for (; i + 4 <= r1; i += 4) {
    const int s0 = csr_src[i + 0];
    const int s1 = csr_src[i + 1];
    const int s2 = csr_src[i + 2];
    const int s3 = csr_src[i + 3];
    const float w0 = dinv[s0] * dv;
    const float w1 = dinv[s1] * dv;
    const float w2 = dinv[s2] * dv;
    const float w3 = dinv[s3] * dv;
    const float2 g0 = h2[(size_t)s0 * 10 + cp];
    const float2 g1 = h2[(size_t)s1 * 10 + cp];
    const float2 g2 = h2[(size_t)s2 * 10 + cp];
    const float2 g3 = h2[(size_t)s3 * 10 + cp];
    acc.x = fmaf(g0.x, w0, acc.x); acc.y = fmaf(g0.y, w0, acc.y);
    acc.x = fmaf(g1.x, w1, acc.x); acc.y = fmaf(g1.y, w1, acc.y);
    acc.x = fmaf(g2.x, w2, acc.x); acc.y = fmaf(g2.y, w2, acc.y);
    acc.x = fmaf(g3.x, w3, acc.x); acc.y = fmaf(g3.y, w3, acc.y);
  }
  for (; i < r1; ++i) {
    const int s = csr_src[i];
    const float w = dinv[s] * dv;
    const float2 g = h2[(size_t)s * 10 + cp];
    acc.x = fmaf(g.x, w, acc.x);
    acc.y = fmaf(g.y, w, acc.y);
  }
  const float2 bv = ((const float2*)bias)[cp];
  float2 v;
  v.x = acc.x + bv.x;
  v.y = acc.y + bv.y;
  ((float2*)out)[(size_t)node * 10 + cp] = v;
}

// ---------------- launch ----------------

extern "C" void kernel_launch(void* const* d_in, const int* in_sizes, int n_in,
                              void* d_out, int out_size, void* d_ws, size_t ws_size,
                              hipStream_t stream) {
  const float* x   = (const float*)d_in[0];
  const int*   ei  = (const int*)d_in[1];
  const float* W1  = (const float*)d_in[2];
  const float* b1  = (const float*)d_in[3];
  const float* W2  = (const float*)d_in[4];
  const float* b2  = (const float*)d_in[5];
  float* out = (float*)d_out;

  const int* srcp = ei;        // edge_index[0]
  const int* dstp = ei + NE;   // edge_index[1]

  // workspace layout (~59 MB)
  char* ws = (char*)d_ws;
  size_t off = 0;
  auto take = [&](size_t bytes) -> char* {
    char* p = ws + off;
    off = (off + bytes + 255) & ~(size_t)255;
    return p;
  };
  int*   cnt     = (int*)take((size_t)NN * 4);
  int*   rowptr  = (int*)take((size_t)(NN + 1) * 4);
  float* dinv    = (float*)take((size_t)NN * 4);
  int*   bsums   = (int*)take(256 * 4);
  int*   cntb    = (int*)take((size_t)NCH * NN * 4);  // 12.8 MB chunk histograms
  int*   csr_src = (int*)take((size_t)NE * 4);
  float* h1      = (float*)take((size_t)NN * CHID * 4);
  float* t1      = (float*)take((size_t)NN * CHID * 4);
  float* g2      = h1;  // h1 dead after agg1; reuse for layer-2 GEMM output

  (void)in_sizes; (void)n_in; (void)out_size; (void)ws_size;

  const int nb = (NN + 1023) / 1024;  // 98

  k_histA<<<NCH * NRANGE, 1024, 0, stream>>>(dstp, cntb);
  k_merge<<<(NN + 255) / 256, 256, 0, stream>>>(cntb, cnt, NN);
  k_scanA<<<nb, 256, 0, stream>>>(cnt, rowptr, bsums, dinv, NN);
  k_scanB<<<1, 256, 0, stream>>>(bsums, nb);
  k_scanC<<<(NN + 255) / 256, 256, 0, stream>>>(rowptr, bsums, NN, NE);
  k_histFill<<<NCH * NRANGE, 1024, 0, stream>>>(srcp, dstp, rowptr, cntb, csr_src);

  k_gemm1<<<(NN + 63) / 64, 256, 0, stream>>>(x, W1, h1, NN);
  const int nwaves1 = (NN + 2) / 3;            // 3 nodes per wave
  k_agg40<<<(nwaves1 + 3) / 4, 256, 0, stream>>>(h1, rowptr, csr_src, dinv, b1, t1, NN);
  k_gemm2<<<(NN + 255) / 256, 256, 0, stream>>>(t1, W2, g2, NN);
  const int nwaves2 = (NN + 5) / 6;            // 6 nodes per wave
  k_agg20<<<(nwaves2 + 3) / 4, 256, 0, stream>>>(g2, rowptr, csr_src, dinv, b2, out, NN);
}